// Round 2
// baseline (119.654 us; speedup 1.0000x reference)
//
#include <hip/hip_runtime.h>
#include <float.h>

// Bidirectional chamfer, B=4, N=M=5000, D=3, fp32.
// out = [ sum_i min_j d2 + sum_j min_i d2 ] / (B*N)   (both means over 20000 rows)
// Per-pair: min_j (|g|^2 - 2 q.g), add |q|^2 after the loop (min/clamp commute).

#define BB      4
#define NP      5000
#define NROWS   (2 * BB * NP)     // 40000
#define THREADS 256
#define ROWS    5
#define QPB     (THREADS * ROWS)  // 1280
#define QBLKS   4                 // 4*1280 = 5120 >= 5000
#define JC      16
#define CHUNK   313               // 16*313 = 5008 >= 5000
#define CHUNKP  316               // padded to multiple of 4 (sentinel entries)
#define GRID    (QBLKS * JC * 2 * BB)  // 512 blocks = 2 per CU
#define BIGF    3.0e38f

__global__ __launch_bounds__(256) void dl_init_kernel(unsigned* __restrict__ ws) {
    int i = blockIdx.x * 256 + threadIdx.x;
    if (i < NROWS) ws[i] = 0x7F7FFFFFu;   // FLT_MAX bits
    if (i == NROWS) ws[i] = 0u;           // block-completion counter
}

__global__ __launch_bounds__(THREADS) void dl_chamfer_kernel(
    const float* __restrict__ pred, const float* __restrict__ gt,
    unsigned* __restrict__ rowmin,     // [2][BB*NP]
    unsigned* __restrict__ counter,    // 1 slot, zeroed by init
    float* __restrict__ out) {
    const int qblk  = blockIdx.x;
    const int chunk = blockIdx.y;
    const int bz    = blockIdx.z;
    const int b     = bz >> 1;
    const int dir   = bz & 1;

    const float* qsrc = dir ? gt   : pred;
    const float* tsrc = dir ? pred : gt;

    // Stage target chunk (x,y,z,|g|^2) into LDS; pad with +huge sentinel so
    // the j-loop needs no remainder handling. Reads below are wave-uniform
    // => bank broadcast, conflict-free.
    __shared__ float4 tg[CHUNKP];
    const int jbase = chunk * CHUNK;
    for (int j = threadIdx.x; j < CHUNKP; j += THREADS) {
        const int gj = jbase + j;
        float4 v;
        if (j < CHUNK && gj < NP) {
            const float* p = tsrc + ((size_t)b * NP + gj) * 3;
            const float x = p[0], y = p[1], z = p[2];
            v = make_float4(x, y, z, x * x + y * y + z * z);
        } else {
            v = make_float4(0.f, 0.f, 0.f, BIGF);  // never wins the min
        }
        tg[j] = v;
    }
    __syncthreads();

    // 5 query rows per thread: amortize the broadcast LDS read over 25 VALU
    // ops (VALU 50 cyc/wave-j vs LDS 12 cyc/wave-j => VALU-bound per CU).
    const int q0 = qblk * QPB + threadIdx.x;
    float qx[ROWS], qy[ROWS], qz[ROWS], m[ROWS];
    #pragma unroll
    for (int r = 0; r < ROWS; ++r) {
        const int q = q0 + r * THREADS;
        const float* p = qsrc + ((size_t)b * NP + (q < NP ? q : 0)) * 3;
        qx[r] = p[0]; qy[r] = p[1]; qz[r] = p[2];
        m[r] = BIGF;
    }

    #pragma unroll 4
    for (int j = 0; j < CHUNKP; ++j) {
        const float4 g = tg[j];
        #pragma unroll
        for (int r = 0; r < ROWS; ++r) {
            float t = qx[r] * g.x;              // q.g via mul + 2 fma
            t = fmaf(qy[r], g.y, t);
            t = fmaf(qz[r], g.z, t);
            const float d = fmaf(-2.0f, t, g.w); // |g|^2 - 2 q.g
            m[r] = fminf(m[r], d);
        }
    }

    // d2 = max(|q|^2 + m, 0); float bits of non-neg floats order as u32.
    unsigned* base = rowmin + (size_t)dir * (BB * NP) + (size_t)b * NP;
    #pragma unroll
    for (int r = 0; r < ROWS; ++r) {
        const int q = q0 + r * THREADS;
        if (q < NP) {
            const float qsq = qx[r] * qx[r] + qy[r] * qy[r] + qz[r] * qz[r];
            const float d2 = fmaxf(qsq + m[r], 0.0f);
            atomicMin(base + q, __float_as_uint(d2));
        }
    }

    // ---- last-block fused reduction ----
    __syncthreads();  // drains vmcnt: all this block's atomics complete
    __shared__ unsigned lastFlag;
    if (threadIdx.x == 0) {
        __threadfence();
        lastFlag = (atomicAdd(counter, 1u) == GRID - 1) ? 1u : 0u;
    }
    __syncthreads();
    if (lastFlag) {
        __threadfence();
        float s = 0.0f;
        for (int i = threadIdx.x; i < NROWS; i += THREADS) {
            // agent-scope load: bypass per-XCD L2 (atomicMin results live at
            // the device coherent point; plain loads could see stale lines)
            unsigned u = __hip_atomic_load(rowmin + i, __ATOMIC_RELAXED,
                                           __HIP_MEMORY_SCOPE_AGENT);
            s += __uint_as_float(u);
        }
        #pragma unroll
        for (int off = 32; off > 0; off >>= 1)
            s += __shfl_down(s, off, 64);
        __shared__ float wsum[THREADS / 64];
        const int wave = threadIdx.x >> 6;
        if ((threadIdx.x & 63) == 0) wsum[wave] = s;
        __syncthreads();
        if (threadIdx.x == 0) {
            float t = 0.0f;
            #pragma unroll
            for (int w = 0; w < THREADS / 64; ++w) t += wsum[w];
            out[0] = t / (float)(BB * NP);
        }
    }
}

extern "C" void kernel_launch(void* const* d_in, const int* in_sizes, int n_in,
                              void* d_out, int out_size, void* d_ws, size_t ws_size,
                              hipStream_t stream) {
    const float* pred = (const float*)d_in[0];
    const float* gt   = (const float*)d_in[1];
    unsigned* rowmin  = (unsigned*)d_ws;           // 40000 u32
    unsigned* counter = rowmin + NROWS;            // 1 u32
    float* out        = (float*)d_out;

    dl_init_kernel<<<dim3((NROWS + 256) / 256 + 1), 256, 0, stream>>>(rowmin);
    dim3 grid(QBLKS, JC, 2 * BB);
    dl_chamfer_kernel<<<grid, THREADS, 0, stream>>>(pred, gt, rowmin, counter, out);
}

// Round 3
// 90.191 us; speedup vs baseline: 1.3267x; 1.3267x over previous
//
#include <hip/hip_runtime.h>

// Bidirectional chamfer, B=4, N=M=5000, D=3, fp32.
// out = sum over both directions of row-min d2, / 20000.
// Wave-internal min: each wave owns QW=10 queries; 64 lanes split all targets;
// shfl_xor butterfly combines. No atomicMin, no rowmin array.

#define BB      4
#define NP      5000
#define THREADS 256
#define NWAVES  4                 // waves per block
#define QW      10                // queries per wave
#define QB      (NWAVES * QW)     // 40 queries per block
#define XBLKS   (NP / QB)         // 125 (exact: 125*40 = 5000)
#define GRID    (XBLKS * 2 * BB)  // 1000 blocks ~= 4 per CU
#define CN      1024              // targets per LDS chunk (float4 = 16 KB)
#define NCHUNK  5                 // 5*1024 = 5120 >= 5000 (sentinel-padded)
#define KPL     (CN / 64)         // 16 j's per lane per chunk
#define BIGF    3.0e38f

__global__ __launch_bounds__(64) void dl_init_kernel(unsigned* __restrict__ counter) {
    if (threadIdx.x == 0) counter[0] = 0u;
}

__global__ __launch_bounds__(THREADS) void dl_chamfer_kernel(
    const float* __restrict__ pred, const float* __restrict__ gt,
    float* __restrict__ partials,      // [GRID]
    unsigned* __restrict__ counter,    // zeroed by init
    float* __restrict__ out) {
    const int qblk = blockIdx.x;            // 0..124
    const int bz   = blockIdx.y;            // 0..7
    const int b    = bz >> 1;
    const int dir  = bz & 1;
    const float* qsrc = dir ? gt   : pred;
    const float* tsrc = dir ? pred : gt;

    const int lane = threadIdx.x & 63;
    const int wave = __builtin_amdgcn_readfirstlane(threadIdx.x >> 6);

    // ---- load this wave's 10 queries (wave-uniform), precompute -2q and |q|^2
    float qsx[QW], qsy[QW], qsz[QW], q2[QW], m[QW];
    const int qbase = qblk * QB + wave * QW;
    const float* qp = qsrc + ((size_t)b * NP + qbase) * 3;
    #pragma unroll
    for (int r = 0; r < QW; ++r) {
        const float x = qp[3 * r], y = qp[3 * r + 1], z = qp[3 * r + 2];
        qsx[r] = -2.0f * x; qsy[r] = -2.0f * y; qsz[r] = -2.0f * z;
        q2[r]  = x * x + y * y + z * z;
        m[r]   = BIGF;
    }

    // ---- main loop: stage target chunk in LDS, lanes split the chunk
    __shared__ float4 tg[CN];
    const float* tb = tsrc + (size_t)b * NP * 3;
    for (int c = 0; c < NCHUNK; ++c) {
        __syncthreads();  // previous chunk's readers done
        #pragma unroll
        for (int i = 0; i < CN / THREADS; ++i) {
            const int e = i * THREADS + threadIdx.x;   // lane-consecutive LDS write
            const int p = c * CN + e;
            float4 v;
            if (p < NP) {
                const float x = tb[3 * p], y = tb[3 * p + 1], z = tb[3 * p + 2];
                v = make_float4(x, y, z, x * x + y * y + z * z);
            } else {
                v = make_float4(0.f, 0.f, 0.f, BIGF);  // sentinel never wins
            }
            tg[e] = v;
        }
        __syncthreads();

        #pragma unroll 4
        for (int k = 0; k < KPL; ++k) {
            const float4 g = tg[k * 64 + lane];        // conflict-free b128
            #pragma unroll
            for (int r = 0; r < QW; ++r) {
                // |g|^2 - 2 q.g  (3 fma + min per pair)
                float d = __builtin_fmaf(qsz[r], g.z, g.w);
                d = __builtin_fmaf(qsy[r], g.y, d);
                d = __builtin_fmaf(qsx[r], g.x, d);
                m[r] = fminf(m[r], d);
            }
        }
    }

    // ---- cross-lane min butterfly (64 lanes covered disjoint targets)
    #pragma unroll
    for (int r = 0; r < QW; ++r) {
        float v = m[r];
        #pragma unroll
        for (int off = 1; off < 64; off <<= 1)
            v = fminf(v, __shfl_xor(v, off, 64));
        m[r] = v;
    }

    // ---- per-wave row sum: d2 = max(|q|^2 + m, 0)
    __shared__ float wsum[NWAVES];
    if (lane == 0) {
        float s = 0.0f;
        #pragma unroll
        for (int r = 0; r < QW; ++r)
            s += fmaxf(q2[r] + m[r], 0.0f);
        wsum[wave] = s;
    }
    __syncthreads();

    const int bid = blockIdx.y * XBLKS + blockIdx.x;
    __shared__ unsigned lastFlag;
    if (threadIdx.x == 0) {
        partials[bid] = wsum[0] + wsum[1] + wsum[2] + wsum[3];
        __threadfence();
        lastFlag = (atomicAdd(counter, 1u) == GRID - 1) ? 1u : 0u;
    }
    __syncthreads();

    // ---- last-block finalize: sum 1000 partials
    if (lastFlag) {
        __threadfence();
        float s = 0.0f;
        for (int i = threadIdx.x; i < GRID; i += THREADS) {
            // agent-scope load: other blocks' partials live past per-XCD L2
            s += __hip_atomic_load((const float*)partials + i, __ATOMIC_RELAXED,
                                   __HIP_MEMORY_SCOPE_AGENT);
        }
        #pragma unroll
        for (int off = 32; off > 0; off >>= 1)
            s += __shfl_down(s, off, 64);
        __shared__ float fsum[NWAVES];
        if (lane == 0) fsum[wave] = s;
        __syncthreads();
        if (threadIdx.x == 0)
            out[0] = (fsum[0] + fsum[1] + fsum[2] + fsum[3]) / (float)(BB * NP);
    }
}

extern "C" void kernel_launch(void* const* d_in, const int* in_sizes, int n_in,
                              void* d_out, int out_size, void* d_ws, size_t ws_size,
                              hipStream_t stream) {
    const float* pred = (const float*)d_in[0];
    const float* gt   = (const float*)d_in[1];
    unsigned* counter = (unsigned*)d_ws;                 // 1 u32
    float* partials   = (float*)d_ws + 16;               // GRID floats, 64B-offset
    float* out        = (float*)d_out;

    dl_init_kernel<<<1, 64, 0, stream>>>(counter);
    dl_chamfer_kernel<<<dim3(XBLKS, 2 * BB), THREADS, 0, stream>>>(
        pred, gt, partials, counter, out);
}